// Round 4
// baseline (113.883 us; speedup 1.0000x reference)
//
#include <hip/hip_runtime.h>
#include <math.h>

// B=64, C=256, HW=256, HEADS=8, HEAD_DIM=256, HID=2048, TEMB=512
// Identity: einsum 'bhnm,bhcl->bhml' contracts n,c independently =>
// softmaxes sum to 1 => q,k irrelevant; pre-projection output is
// SC^2 * colsum of v, constant over spatial l.
// Single kernel, 4 phases, 3 manual grid barriers. All dot-products put
// the reduction axis on lanes => contiguous weight reads + shfl tree.

static constexpr float EPSV = 1e-6f;
static constexpr float SC2 = 1.0f / 256.0f;   // SC^2, SC = 256^-0.5

#define NBLK 256
#define NTHR 512

__device__ __forceinline__ void grid_sync(unsigned* cnt, unsigned* gen) {
    __syncthreads();
    if (threadIdx.x == 0) {
        unsigned g = __hip_atomic_load(gen, __ATOMIC_RELAXED,
                                       __HIP_MEMORY_SCOPE_AGENT);
        unsigned prev = __hip_atomic_fetch_add(cnt, 1u, __ATOMIC_ACQ_REL,
                                               __HIP_MEMORY_SCOPE_AGENT);
        if (prev == NBLK - 1) {
            __hip_atomic_store(cnt, 0u, __ATOMIC_RELAXED,
                               __HIP_MEMORY_SCOPE_AGENT);
            __hip_atomic_store(gen, g + 1u, __ATOMIC_RELEASE,
                               __HIP_MEMORY_SCOPE_AGENT);
        } else {
            while (__hip_atomic_load(gen, __ATOMIC_RELAXED,
                                     __HIP_MEMORY_SCOPE_AGENT) == g)
                __builtin_amdgcn_s_sleep(1);
            (void)__hip_atomic_load(gen, __ATOMIC_ACQUIRE,
                                    __HIP_MEMORY_SCOPE_AGENT);
        }
    }
    __syncthreads();
}

__device__ __forceinline__ float wave_sum(float v) {
    v += __shfl_xor(v, 1);  v += __shfl_xor(v, 2);
    v += __shfl_xor(v, 4);  v += __shfl_xor(v, 8);
    v += __shfl_xor(v, 16); v += __shfl_xor(v, 32);
    return v;
}

__global__ void __launch_bounds__(NTHR) k_fused(
    const float* __restrict__ x, const float* __restrict__ temb,
    const float* __restrict__ mlp_w, const float* __restrict__ mlp_b,
    const float* __restrict__ qkv_w, const float* __restrict__ out_w,
    const float* __restrict__ out_b, const float* __restrict__ onorm,
    float* __restrict__ out, float* __restrict__ ws)
{
    __shared__ float smem[8192];                   // 32 KB, reused per phase
    unsigned* cnt = (unsigned*)ws;
    unsigned* gen = ((unsigned*)ws) + 1;
    float* scsh = ws + 1024;     // [64 b][512 j]      32768
    float* wvp  = ws + 34816;    // [64 chunk][256 ci] 16384
    float* of   = ws + 51200;    // [64 b][2048 o]     131072
    float* yv   = ws + 182272;   // [64 b][256 c]      16384

    const int blk = blockIdx.x, tid = threadIdx.x;
    const int wv = tid >> 6, lane = tid & 63;

    // ---------------- P1: time-MLP (per-b) + Wv column-sums ----------
    if (blk < 64) {
        // scsh[b][j] = silu(temb[b]) . mlp_w[j] + mlp_b[j], b = blk
        int b = blk;
        float* sl = smem;                  // silu(temb[b, 0..511])
        float v = temb[b * 512 + tid];
        sl[tid] = v / (1.0f + expf(-v));
        __syncthreads();
        // wave wv handles j = wv*64 .. +63; lane = t-slice (coalesced)
        for (int jj = 0; jj < 64; ++jj) {
            int j = wv * 64 + jj;
            const float* wr = mlp_w + (size_t)j * 512;
            float a0 = 0.f, a1 = 0.f;
#pragma unroll
            for (int k = 0; k < 8; k += 2) {
                a0 = fmaf(wr[(k + 0) * 64 + lane], sl[(k + 0) * 64 + lane], a0);
                a1 = fmaf(wr[(k + 1) * 64 + lane], sl[(k + 1) * 64 + lane], a1);
            }
            float a = wave_sum(a0 + a1);
            if (lane == 0) scsh[b * 512 + j] = a + mlp_b[j];
        }
    } else if (blk < 128) {
        // wvp[w][ci]: 32-row partial column-sum of qkv_w's v-block
        int w = blk - 64;
        int ci = tid & 255, half = tid >> 8;
        const float* base =
            qkv_w + (size_t)(4096 + w * 32 + half * 16) * 256 + ci;
        float s = 0.f;
#pragma unroll
        for (int r = 0; r < 16; ++r) s += base[(size_t)r * 256];
        smem[half * 256 + ci] = s;
        __syncthreads();
        if (tid < 256) wvp[w * 256 + tid] = smem[tid] + smem[256 + tid];
    }

    grid_sync(cnt, gen);

    // ---------------- P2: x-pass -> of[b][2048] ----------------------
    {
        int q = blk & 3, b = blk >> 2;
        float* coef  = smem;               // [256 c][8 h]      2048
        float* red   = smem + 2048;        // [8 w][16 mt][36]  4608
        float* ssh   = smem + 6656;        // [8]
        float* parts = smem + 6664;        // [4][8]

        if (tid < 256) {
            int c = tid;
            float sc = 1.0f + scsh[b * 512 + c];
            float sh = scsh[b * 512 + 256 + c];
#pragma unroll
            for (int h = 0; h < 8; ++h) {
                float wvv = 0.f;
#pragma unroll
                for (int k = 0; k < 8; ++k) wvv += wvp[(h * 8 + k) * 256 + c];
                coef[c * 8 + h] = sc * wvv;
                float sv = wave_sum(sh * wvv);
                if ((tid & 63) == 0) parts[(tid >> 6) * 8 + h] = sv;
            }
        }
        __syncthreads();
        if (tid < 8)
            ssh[tid] = parts[tid] + parts[8 + tid] +
                       parts[16 + tid] + parts[24 + tid];

        // acc[h*4+mi] = A[h] for 4 m's, acc[32+mi] = ss2
        int mt = tid & 15, cg = tid >> 4;  // cg 0..31, 8 c each
        float acc[36];
#pragma unroll
        for (int i = 0; i < 36; ++i) acc[i] = 0.f;
        const float4* x4 = reinterpret_cast<const float4*>(x) +
                           (size_t)b * 16384 + q * 16 + mt;
#pragma unroll
        for (int ci = 0; ci < 8; ++ci) {
            int c = cg * 8 + ci;
            float4 xv = x4[(size_t)c * 64];
            float xa[4] = {xv.x, xv.y, xv.z, xv.w};
            const float4 cf0 = *reinterpret_cast<const float4*>(&coef[c * 8]);
            const float4 cf1 =
                *reinterpret_cast<const float4*>(&coef[c * 8 + 4]);
            float cf[8] = {cf0.x, cf0.y, cf0.z, cf0.w,
                           cf1.x, cf1.y, cf1.z, cf1.w};
#pragma unroll
            for (int h = 0; h < 8; ++h)
#pragma unroll
                for (int mi = 0; mi < 4; ++mi)
                    acc[h * 4 + mi] = fmaf(xa[mi], cf[h], acc[h * 4 + mi]);
#pragma unroll
            for (int mi = 0; mi < 4; ++mi)
                acc[32 + mi] = fmaf(xa[mi], xa[mi], acc[32 + mi]);
        }
#pragma unroll
        for (int i = 0; i < 36; ++i) {
            acc[i] += __shfl_xor(acc[i], 16);
            acc[i] += __shfl_xor(acc[i], 32);
        }
        if (lane < 16) {
#pragma unroll
            for (int i = 0; i < 36; ++i)
                red[(wv * 16 + lane) * 36 + i] = acc[i];
        }
        __syncthreads();
        if (tid < 16) {
            float fin[36];
#pragma unroll
            for (int i = 0; i < 36; ++i) {
                float s = 0.f;
#pragma unroll
                for (int w = 0; w < 8; ++w) s += red[(w * 16 + tid) * 36 + i];
                fin[i] = s;
            }
            float invv[4];
#pragma unroll
            for (int mi = 0; mi < 4; ++mi)
                invv[mi] = rsqrtf(fin[32 + mi] * (1.0f / 256.0f) + EPSV);
            float4* o4 = reinterpret_cast<float4*>(of);
#pragma unroll
            for (int h = 0; h < 8; ++h) {
                float4 r;
                r.x = SC2 * fmaf(invv[0], fin[h * 4 + 0], ssh[h]);
                r.y = SC2 * fmaf(invv[1], fin[h * 4 + 1], ssh[h]);
                r.z = SC2 * fmaf(invv[2], fin[h * 4 + 2], ssh[h]);
                r.w = SC2 * fmaf(invv[3], fin[h * 4 + 3], ssh[h]);
                o4[b * 512 + h * 64 + q * 16 + tid] = r;   // of[b][h*256+m]
            }
        }
    }

    grid_sync(cnt, gen);

    // ---------------- P2b: y[c] = of[b] . out_w[c,:]  (lane = o) -----
    {
        int cq = blk & 3, b = blk >> 2;
        float* ofs = smem;                 // [2048]
        for (int i = tid; i < 2048; i += NTHR) ofs[i] = of[b * 2048 + i];
        __syncthreads();
#pragma unroll
        for (int cc = 0; cc < 8; ++cc) {
            int c = cq * 64 + wv * 8 + cc;
            const float* wrow = out_w + (size_t)c * 2048;
            float a0 = 0.f, a1 = 0.f, a2 = 0.f, a3 = 0.f;
#pragma unroll
            for (int k = 0; k < 32; k += 4) {
                a0 = fmaf(wrow[(k + 0) * 64 + lane], ofs[(k + 0) * 64 + lane], a0);
                a1 = fmaf(wrow[(k + 1) * 64 + lane], ofs[(k + 1) * 64 + lane], a1);
                a2 = fmaf(wrow[(k + 2) * 64 + lane], ofs[(k + 2) * 64 + lane], a2);
                a3 = fmaf(wrow[(k + 3) * 64 + lane], ofs[(k + 3) * 64 + lane], a3);
            }
            float a = wave_sum((a0 + a1) + (a2 + a3));
            if (lane == 0) yv[b * 256 + c] = a + out_b[c];
        }
    }

    grid_sync(cnt, gen);

    // ---------------- P3: per-b RMS (redundant x4) + stream ----------
    {
        int q = blk & 3, b = blk >> 2;
        float* g = smem;                   // [256]
        float* wred = smem + 256;          // [4]
        float ybc = 0.f;
        if (tid < 256) {
            ybc = yv[b * 256 + tid];
            float v2 = wave_sum(ybc * ybc);
            if ((tid & 63) == 0) wred[tid >> 6] = v2;
        }
        __syncthreads();
        float tot = wred[0] + wred[1] + wred[2] + wred[3];
        float inv2 = rsqrtf(tot * (1.0f / 256.0f) + EPSV);
        if (tid < 256) g[tid] = ybc * inv2 * onorm[tid];
        __syncthreads();

        const float4* xx = reinterpret_cast<const float4*>(x) +
                           (size_t)b * 16384 + q * 16;
        float4* oo = reinterpret_cast<float4*>(out) +
                     (size_t)b * 16384 + q * 16;
#pragma unroll
        for (int i = tid; i < 4096; i += NTHR) {
            int row = i >> 4, col = i & 15;
            float4 xv = xx[(size_t)row * 64 + col];
            float gg = g[row];
            oo[(size_t)row * 64 + col] =
                make_float4(xv.x + gg, xv.y + gg, xv.z + gg, xv.w + gg);
        }
    }
}

extern "C" void kernel_launch(void* const* d_in, const int* in_sizes, int n_in,
                              void* d_out, int out_size, void* d_ws, size_t ws_size,
                              hipStream_t stream) {
    const float* x     = (const float*)d_in[0];
    const float* temb  = (const float*)d_in[1];
    const float* mlp_w = (const float*)d_in[2];
    const float* mlp_b = (const float*)d_in[3];
    const float* qkv_w = (const float*)d_in[4];
    const float* out_w = (const float*)d_in[5];
    const float* out_b = (const float*)d_in[6];
    const float* onorm = (const float*)d_in[7];
    float* out = (float*)d_out;
    float* ws  = (float*)d_ws;

    hipMemsetAsync(ws, 0, 64, stream);   // barrier counters
    k_fused<<<NBLK, NTHR, 0, stream>>>(x, temb, mlp_w, mlp_b, qkv_w,
                                       out_w, out_b, onorm, out, ws);
}

// Round 5
// 74.582 us; speedup vs baseline: 1.5269x; 1.5269x over previous
//
#include <hip/hip_runtime.h>
#include <math.h>

// B=64, C=256, HW=256, HEADS=8, HEAD_DIM=256, HID=2048, TEMB=512
// Identity: einsum 'bhnm,bhcl->bhml' contracts n,c independently =>
// softmaxes sum to 1 => q,k irrelevant; pre-projection output is
// SC^2 * colsum of v, constant over spatial l.
// 4 kernels, no grid barriers (256-way agent-scope barrier measured
// ~20-30us each in R3/R4). Every hot access coalesced / LDS-broadcast.

static constexpr float EPSV = 1e-6f;
static constexpr float SC2 = 1.0f / 256.0f;   // SC^2, SC = 256^-0.5

__device__ __forceinline__ float wave_sum(float v) {
    v += __shfl_xor(v, 1);  v += __shfl_xor(v, 2);
    v += __shfl_xor(v, 4);  v += __shfl_xor(v, 8);
    v += __shfl_xor(v, 16); v += __shfl_xor(v, 32);
    return v;
}

// ---------------- K1: time-MLP + Wv chunk column-sums -------------------
// blocks 0..255 : (b, jq). scsh[b][j] = silu(temb[b]).mlp_w[j] + mlp_b[j]
//                 lane = t (coalesced mlp_w row reads), 32 j per wave.
// blocks 256..319: wvp[w][ci] = 32-row partial colsum of qkv_w v-block.
__global__ void __launch_bounds__(256) k1_prep(
    const float* __restrict__ temb, const float* __restrict__ mlp_w,
    const float* __restrict__ mlp_b, const float* __restrict__ qkv_w,
    float* __restrict__ scsh, float* __restrict__ wvp)
{
    const int blk = blockIdx.x, tid = threadIdx.x;
    const int wv = tid >> 6, lane = tid & 63;
    if (blk < 256) {
        int b = blk >> 2, jq = blk & 3;
        __shared__ float sl[512];
        float v0 = temb[b * 512 + tid];
        float v1 = temb[b * 512 + 256 + tid];
        sl[tid] = v0 / (1.0f + expf(-v0));
        sl[256 + tid] = v1 / (1.0f + expf(-v1));
        __syncthreads();
        for (int jj = 0; jj < 32; ++jj) {
            int j = jq * 128 + wv * 32 + jj;
            const float* wr = mlp_w + (size_t)j * 512;
            float a0 = 0.f, a1 = 0.f;
#pragma unroll
            for (int k = 0; k < 8; k += 2) {
                a0 = fmaf(wr[(k + 0) * 64 + lane], sl[(k + 0) * 64 + lane], a0);
                a1 = fmaf(wr[(k + 1) * 64 + lane], sl[(k + 1) * 64 + lane], a1);
            }
            float a = wave_sum(a0 + a1);
            if (lane == 0) scsh[b * 512 + j] = a + mlp_b[j];
        }
    } else {
        int w = blk - 256;                 // 0..63
        const float* base = qkv_w + (size_t)(4096 + w * 32) * 256 + tid;
        float s = 0.f;
#pragma unroll
        for (int r = 0; r < 32; ++r) s += base[(size_t)r * 256];
        wvp[w * 256 + tid] = s;
    }
}

// ---------------- K2: x-pass -> ofT[o][b] -------------------------------
// grid 256 = (b, m-quarter q); 512 threads = cg(32) x mt(16), 4 m each.
__global__ void __launch_bounds__(512) k2_vpass(
    const float* __restrict__ x, const float* __restrict__ scsh,
    const float* __restrict__ wvp, float* __restrict__ ofT)
{
    const int blk = blockIdx.x, tid = threadIdx.x;
    const int wv = tid >> 6, lane = tid & 63;
    const int q = blk & 3, b = blk >> 2;

    __shared__ float coef[256 * 8];        // [c][h]
    __shared__ float red[8 * 16 * 36];     // [w][mt][36]
    __shared__ float ssh[8];
    __shared__ float parts[4 * 8];

    if (tid < 256) {
        int c = tid;
        float sc = 1.0f + scsh[b * 512 + c];
        float sh = scsh[b * 512 + 256 + c];
#pragma unroll
        for (int h = 0; h < 8; ++h) {
            float wvv = 0.f;
#pragma unroll
            for (int k = 0; k < 8; ++k) wvv += wvp[(h * 8 + k) * 256 + c];
            coef[c * 8 + h] = sc * wvv;
            float sv = wave_sum(sh * wvv);
            if ((tid & 63) == 0) parts[(tid >> 6) * 8 + h] = sv;
        }
    }
    __syncthreads();
    if (tid < 8)
        ssh[tid] = parts[tid] + parts[8 + tid] + parts[16 + tid] + parts[24 + tid];

    // acc[h*4+mi] = A[h], acc[32+mi] = ss2
    int mt = tid & 15, cg = tid >> 4;      // cg 0..31, 8 c each
    float acc[36];
#pragma unroll
    for (int i = 0; i < 36; ++i) acc[i] = 0.f;
    const float4* x4 = reinterpret_cast<const float4*>(x) +
                       (size_t)b * 16384 + q * 16 + mt;
#pragma unroll
    for (int ci = 0; ci < 8; ++ci) {
        int c = cg * 8 + ci;
        float4 xv = x4[(size_t)c * 64];
        float xa[4] = {xv.x, xv.y, xv.z, xv.w};
        const float4 cf0 = *reinterpret_cast<const float4*>(&coef[c * 8]);
        const float4 cf1 = *reinterpret_cast<const float4*>(&coef[c * 8 + 4]);
        float cf[8] = {cf0.x, cf0.y, cf0.z, cf0.w, cf1.x, cf1.y, cf1.z, cf1.w};
#pragma unroll
        for (int h = 0; h < 8; ++h)
#pragma unroll
            for (int mi = 0; mi < 4; ++mi)
                acc[h * 4 + mi] = fmaf(xa[mi], cf[h], acc[h * 4 + mi]);
#pragma unroll
        for (int mi = 0; mi < 4; ++mi)
            acc[32 + mi] = fmaf(xa[mi], xa[mi], acc[32 + mi]);
    }
#pragma unroll
    for (int i = 0; i < 36; ++i) {
        acc[i] += __shfl_xor(acc[i], 16);
        acc[i] += __shfl_xor(acc[i], 32);
    }
    if (lane < 16) {
#pragma unroll
        for (int i = 0; i < 36; ++i)
            red[(wv * 16 + lane) * 36 + i] = acc[i];
    }
    __syncthreads();
    if (tid < 16) {
        float fin[36];
#pragma unroll
        for (int i = 0; i < 36; ++i) {
            float s = 0.f;
#pragma unroll
            for (int w = 0; w < 8; ++w) s += red[(w * 16 + tid) * 36 + i];
            fin[i] = s;
        }
        float invv[4];
#pragma unroll
        for (int mi = 0; mi < 4; ++mi)
            invv[mi] = rsqrtf(fin[32 + mi] * (1.0f / 256.0f) + EPSV);
        // ofT[o][b], o = h*256 + q*64 + tid*4 + mi (scatter, 32 dwords/thr)
#pragma unroll
        for (int h = 0; h < 8; ++h)
#pragma unroll
            for (int mi = 0; mi < 4; ++mi)
                ofT[(size_t)(h * 256 + q * 64 + tid * 4 + mi) * 64 + b] =
                    SC2 * fmaf(invv[mi], fin[h * 4 + mi], ssh[h]);
    }
}

// ---------------- K3: y[b][c] = ofT[.][b] . out_w[c][.] + out_b[c] ------
// 64 blocks x 512 thr; block owns c = blk*4..+3. lane = b (coalesced ofT),
// out_w rows in LDS (read once total), broadcast reads. Waves split o.
__global__ void __launch_bounds__(512) k3_proj(
    const float* __restrict__ ofT, const float* __restrict__ out_w,
    const float* __restrict__ out_b, float* __restrict__ yv)
{
    const int blk = blockIdx.x, tid = threadIdx.x;
    const int wv = tid >> 6, lane = tid & 63;
    __shared__ float wtile[4 * 2048];      // 32 KB
    __shared__ float part[8 * 4 * 64];     // 8 KB

    for (int i = tid; i < 8192; i += 512)
        wtile[i] = out_w[(size_t)blk * 4 * 2048 + i];
    __syncthreads();

    float acc[4] = {0.f, 0.f, 0.f, 0.f};
    const float* ofp = ofT + (size_t)(wv * 256) * 64 + lane;
    const float* wp = wtile + wv * 256;
#pragma unroll 2
    for (int oo = 0; oo < 256; ++oo) {
        float ov = ofp[(size_t)oo * 64];
#pragma unroll
        for (int cc = 0; cc < 4; ++cc)
            acc[cc] = fmaf(ov, wp[cc * 2048 + oo], acc[cc]);
    }
#pragma unroll
    for (int cc = 0; cc < 4; ++cc)
        part[(wv * 4 + cc) * 64 + lane] = acc[cc];
    __syncthreads();

    if (tid < 256) {
        int b = tid & 63, cc = tid >> 6;
        float s = 0.f;
#pragma unroll
        for (int w = 0; w < 8; ++w) s += part[(w * 4 + cc) * 64 + b];
        yv[b * 256 + blk * 4 + cc] = s + out_b[blk * 4 + cc];
    }
}

// ---------------- K4: per-b RMS + g, stream out = x + g -----------------
__global__ void __launch_bounds__(512) k4_fin(
    const float* __restrict__ yv, const float* __restrict__ onorm,
    const float* __restrict__ x, float* __restrict__ out)
{
    const int blk = blockIdx.x, tid = threadIdx.x;
    const int q = blk & 3, b = blk >> 2;
    __shared__ float g[256];
    __shared__ float wred[4];
    if (tid < 256) {
        float yb = yv[b * 256 + tid];
        float v2 = wave_sum(yb * yb);
        if ((tid & 63) == 0) wred[tid >> 6] = v2;
        g[tid] = yb;
    }
    __syncthreads();
    float inv2 = rsqrtf((wred[0] + wred[1] + wred[2] + wred[3]) *
                        (1.0f / 256.0f) + EPSV);
    if (tid < 256) g[tid] = g[tid] * inv2 * onorm[tid];
    __syncthreads();

    const float4* xx = reinterpret_cast<const float4*>(x) +
                       (size_t)b * 16384 + q * 16;
    float4* oo = reinterpret_cast<float4*>(out) + (size_t)b * 16384 + q * 16;
#pragma unroll
    for (int i = tid; i < 4096; i += 512) {
        int row = i >> 4, col = i & 15;
        float4 xv = xx[(size_t)row * 64 + col];
        float gg = g[row];
        oo[(size_t)row * 64 + col] =
            make_float4(xv.x + gg, xv.y + gg, xv.z + gg, xv.w + gg);
    }
}

extern "C" void kernel_launch(void* const* d_in, const int* in_sizes, int n_in,
                              void* d_out, int out_size, void* d_ws, size_t ws_size,
                              hipStream_t stream) {
    const float* x     = (const float*)d_in[0];
    const float* temb  = (const float*)d_in[1];
    const float* mlp_w = (const float*)d_in[2];
    const float* mlp_b = (const float*)d_in[3];
    const float* qkv_w = (const float*)d_in[4];
    const float* out_w = (const float*)d_in[5];
    const float* out_b = (const float*)d_in[6];
    const float* onorm = (const float*)d_in[7];
    float* out = (float*)d_out;
    float* ws  = (float*)d_ws;

    float* scsh = ws;            // [64 b][512 j]   32768
    float* wvp  = ws + 32768;    // [64 w][256 ci]  16384
    float* ofT  = ws + 49152;    // [2048 o][64 b]  131072
    float* yv   = ws + 180224;   // [64 b][256 c]   16384

    k1_prep <<<320, 256, 0, stream>>>(temb, mlp_w, mlp_b, qkv_w, scsh, wvp);
    k2_vpass<<<256, 512, 0, stream>>>(x, scsh, wvp, ofT);
    k3_proj <<<64,  512, 0, stream>>>(ofT, out_w, out_b, yv);
    k4_fin  <<<256, 512, 0, stream>>>(yv, onorm, x, out);
}

// Round 6
// 66.524 us; speedup vs baseline: 1.7119x; 1.1211x over previous
//
#include <hip/hip_runtime.h>
#include <math.h>

// B=64, C=256, HW=256, HEADS=8, HEAD_DIM=256, HID=2048, TEMB=512
// Identity: einsum 'bhnm,bhcl->bhml' contracts n,c independently =>
// softmaxes sum to 1 => q,k irrelevant; pre-projection output is
// SC^2 * colsum of v, constant over spatial l.
//
// ONE kernel, 4 phases, 3 grid barriers. Measured: kernel->kernel graph
// boundary ~13us (R1/R2/R5), single-counter RMW barrier ~25us (R3/R4).
// This uses a flag-array barrier: per-block release-store to own padded
// line (parallel), block0 polls all flags, one gen broadcast (read-spin).

static constexpr float EPSV = 1e-6f;
static constexpr float SC2 = 1.0f / 256.0f;   // SC^2, SC = 256^-0.5

#define NBLK 256
#define NTHR 512

__device__ __forceinline__ float wave_sum(float v) {
    v += __shfl_xor(v, 1);  v += __shfl_xor(v, 2);
    v += __shfl_xor(v, 4);  v += __shfl_xor(v, 8);
    v += __shfl_xor(v, 16); v += __shfl_xor(v, 32);
    return v;
}

// flags[i] at u[i*16] (64B-padded), gen at u[4096]. Zeroed per call.
__device__ __forceinline__ void gsync(unsigned* u, unsigned k) {
    __syncthreads();
    const int tid = threadIdx.x, blk = blockIdx.x;
    if (tid == 0)
        __hip_atomic_store(u + blk * 16, k, __ATOMIC_RELEASE,
                           __HIP_MEMORY_SCOPE_AGENT);
    if (blk == 0) {
        if (tid < 256) {
            unsigned* f = u + tid * 16;
            while (__hip_atomic_load(f, __ATOMIC_RELAXED,
                                     __HIP_MEMORY_SCOPE_AGENT) < k)
                __builtin_amdgcn_s_sleep(1);
            (void)__hip_atomic_load(f, __ATOMIC_ACQUIRE,
                                    __HIP_MEMORY_SCOPE_AGENT);
        }
        __syncthreads();
        if (tid == 0)
            __hip_atomic_store(u + 4096, k, __ATOMIC_RELEASE,
                               __HIP_MEMORY_SCOPE_AGENT);
    } else {
        if (tid == 0) {
            unsigned* g = u + 4096;
            while (__hip_atomic_load(g, __ATOMIC_RELAXED,
                                     __HIP_MEMORY_SCOPE_AGENT) < k)
                __builtin_amdgcn_s_sleep(1);
            (void)__hip_atomic_load(g, __ATOMIC_ACQUIRE,
                                    __HIP_MEMORY_SCOPE_AGENT);
        }
    }
    __syncthreads();
}

__global__ void __launch_bounds__(NTHR) k_fused(
    const float* __restrict__ x, const float* __restrict__ temb,
    const float* __restrict__ mlp_w, const float* __restrict__ mlp_b,
    const float* __restrict__ qkv_w, const float* __restrict__ out_w,
    const float* __restrict__ out_b, const float* __restrict__ onorm,
    float* __restrict__ out, float* __restrict__ ws)
{
    __shared__ float smem[8192];          // 32 KB, re-carved per phase
    unsigned* ubar = (unsigned*)ws;       // flags + gen (zeroed per call)
    float* scsh = ws + 8192;              // [64 b][512 j]
    float* wvp  = ws + 40960;             // [64 w][256 ci]
    float* ofT  = ws + 57344;             // [2048 o][64 b]
    float* part = ws + 188416;            // [4 oq][64 b][256 c]

    const int blk = blockIdx.x, tid = threadIdx.x;
    const int wv = tid >> 6, lane = tid & 63;

    // ========== P1: time-MLP slice + Wv colsum slice (all blocks) ====
    {
        // MLP: b = blk&63, jq = blk>>6 -> j in [jq*128, +128)
        int b = blk & 63, jq = blk >> 6;
        float* sl = smem;                  // [512] silu(temb[b])
        float v = temb[b * 512 + tid];
        sl[tid] = v / (1.0f + expf(-v));
        __syncthreads();
        int j0 = jq * 128 + wv * 16;
#pragma unroll
        for (int g = 0; g < 4; ++g) {
            int j = j0 + g * 4;
            float a0 = 0.f, a1 = 0.f, a2 = 0.f, a3 = 0.f;
#pragma unroll
            for (int k = 0; k < 8; ++k) {
                float slv = sl[k * 64 + lane];
                a0 = fmaf(mlp_w[(size_t)(j + 0) * 512 + k * 64 + lane], slv, a0);
                a1 = fmaf(mlp_w[(size_t)(j + 1) * 512 + k * 64 + lane], slv, a1);
                a2 = fmaf(mlp_w[(size_t)(j + 2) * 512 + k * 64 + lane], slv, a2);
                a3 = fmaf(mlp_w[(size_t)(j + 3) * 512 + k * 64 + lane], slv, a3);
            }
            a0 = wave_sum(a0); a1 = wave_sum(a1);
            a2 = wave_sum(a2); a3 = wave_sum(a3);
            if (lane == 0) {
                scsh[b * 512 + j + 0] = a0 + mlp_b[j + 0];
                scsh[b * 512 + j + 1] = a1 + mlp_b[j + 1];
                scsh[b * 512 + j + 2] = a2 + mlp_b[j + 2];
                scsh[b * 512 + j + 3] = a3 + mlp_b[j + 3];
            }
        }
        // wvp: w = blk>>2, cq = blk&3 -> ci in [cq*64, +64), 32 rows
        int w = blk >> 2, cq = blk & 3;
        float* wvs = smem + 1024;          // [8][64]
        int rg = tid >> 6;                 // 0..7 (4 rows each)
        const float* base =
            qkv_w + (size_t)(4096 + w * 32 + rg * 4) * 256 + cq * 64 + lane;
        float s = base[0] + base[256] + base[512] + base[768];
        wvs[rg * 64 + lane] = s;
        __syncthreads();
        if (tid < 64) {
            float t = 0.f;
#pragma unroll
            for (int r = 0; r < 8; ++r) t += wvs[r * 64 + tid];
            wvp[w * 256 + cq * 64 + tid] = t;
        }
    }

    gsync(ubar, 1);

    // ========== P2: x-pass -> ofT[o][b]  (b = blk>>2, q = blk&3) =====
    {
        int q = blk & 3, b = blk >> 2;
        float* coef  = smem;               // [256 c][8 h]   2048
        float* red   = smem + 2048;        // [8 w][16][36]  4608
        float* ssh   = smem + 6656;        // [8]
        float* parts = smem + 6664;        // [4][8]

        if (tid < 256) {
            int c = tid;
            float sc = 1.0f + scsh[b * 512 + c];
            float sh = scsh[b * 512 + 256 + c];
#pragma unroll
            for (int h = 0; h < 8; ++h) {
                float wvv = 0.f;
#pragma unroll
                for (int k = 0; k < 8; ++k) wvv += wvp[(h * 8 + k) * 256 + c];
                coef[c * 8 + h] = sc * wvv;
                float sv = wave_sum(sh * wvv);
                if ((tid & 63) == 0) parts[(tid >> 6) * 8 + h] = sv;
            }
        }
        __syncthreads();
        if (tid < 8)
            ssh[tid] = parts[tid] + parts[8 + tid] +
                       parts[16 + tid] + parts[24 + tid];

        int mt = tid & 15, cg = tid >> 4;  // cg 0..31, 8 c each
        float acc[36];
#pragma unroll
        for (int i = 0; i < 36; ++i) acc[i] = 0.f;
        const float4* x4 = reinterpret_cast<const float4*>(x) +
                           (size_t)b * 16384 + q * 16 + mt;
#pragma unroll
        for (int ci = 0; ci < 8; ++ci) {
            int c = cg * 8 + ci;
            float4 xv = x4[(size_t)c * 64];
            float xa[4] = {xv.x, xv.y, xv.z, xv.w};
            const float4 cf0 = *reinterpret_cast<const float4*>(&coef[c * 8]);
            const float4 cf1 = *reinterpret_cast<const float4*>(&coef[c * 8 + 4]);
            float cf[8] = {cf0.x, cf0.y, cf0.z, cf0.w,
                           cf1.x, cf1.y, cf1.z, cf1.w};
#pragma unroll
            for (int h = 0; h < 8; ++h)
#pragma unroll
                for (int mi = 0; mi < 4; ++mi)
                    acc[h * 4 + mi] = fmaf(xa[mi], cf[h], acc[h * 4 + mi]);
#pragma unroll
            for (int mi = 0; mi < 4; ++mi)
                acc[32 + mi] = fmaf(xa[mi], xa[mi], acc[32 + mi]);
        }
#pragma unroll
        for (int i = 0; i < 36; ++i) {
            acc[i] += __shfl_xor(acc[i], 16);
            acc[i] += __shfl_xor(acc[i], 32);
        }
        if (lane < 16) {
#pragma unroll
            for (int i = 0; i < 36; ++i)
                red[(wv * 16 + lane) * 36 + i] = acc[i];
        }
        __syncthreads();
        if (tid < 16) {
            float fin[36];
#pragma unroll
            for (int i = 0; i < 36; ++i) {
                float s = 0.f;
#pragma unroll
                for (int w = 0; w < 8; ++w) s += red[(w * 16 + tid) * 36 + i];
                fin[i] = s;
            }
            float invv[4];
#pragma unroll
            for (int mi = 0; mi < 4; ++mi)
                invv[mi] = rsqrtf(fin[32 + mi] * (1.0f / 256.0f) + EPSV);
#pragma unroll
            for (int h = 0; h < 8; ++h)
#pragma unroll
                for (int mi = 0; mi < 4; ++mi)
                    ofT[(size_t)(h * 256 + q * 64 + tid * 4 + mi) * 64 + b] =
                        SC2 * fmaf(invv[mi], fin[h * 4 + mi], ssh[h]);
        }
    }

    gsync(ubar, 2);

    // ========== P3: partial projection (cg = blk>>2, oq = blk&3) =====
    // part[oq][b][c] = sum_{o in oq*512..+511} ofT[o][b] * out_w[c][o]
    {
        int cg = blk >> 2, oq = blk & 3;   // c = cg*4..+3
        float* wtile = smem;               // [4 cc][512 oo]  2048
        float* pbuf  = smem + 2048;        // [8 wv][4 cc][64 b] 2048

        for (int i = tid; i < 2048; i += NTHR) {
            int cc = i >> 9, oo = i & 511;
            wtile[i] = out_w[(size_t)(cg * 4 + cc) * 2048 + oq * 512 + oo];
        }
        __syncthreads();

        float a0 = 0.f, a1 = 0.f, a2 = 0.f, a3 = 0.f;
        const float* ofp = ofT + (size_t)(oq * 512 + wv * 64) * 64 + lane;
        const float* wp = wtile + wv * 64;
#pragma unroll 4
        for (int oo = 0; oo < 64; ++oo) {
            float ov = ofp[(size_t)oo * 64];
            a0 = fmaf(ov, wp[0 * 512 + oo], a0);
            a1 = fmaf(ov, wp[1 * 512 + oo], a1);
            a2 = fmaf(ov, wp[2 * 512 + oo], a2);
            a3 = fmaf(ov, wp[3 * 512 + oo], a3);
        }
        pbuf[(wv * 4 + 0) * 64 + lane] = a0;
        pbuf[(wv * 4 + 1) * 64 + lane] = a1;
        pbuf[(wv * 4 + 2) * 64 + lane] = a2;
        pbuf[(wv * 4 + 3) * 64 + lane] = a3;
        __syncthreads();

        if (tid < 256) {
            int b = tid & 63, cc = tid >> 6;
            float s = 0.f;
#pragma unroll
            for (int w = 0; w < 8; ++w) s += pbuf[(w * 4 + cc) * 64 + b];
            part[(size_t)oq * 16384 + b * 256 + cg * 4 + cc] = s;
        }
    }

    gsync(ubar, 3);

    // ========== P4: y reduce + RMS + g, stream out = x + g ===========
    {
        int q = blk & 3, b = blk >> 2;
        float* g = smem;                   // [256]
        float* wred = smem + 256;          // [4]
        float yb = 0.f;
        if (tid < 256) {
            yb = out_b[tid] +
                 part[b * 256 + tid] + part[16384 + b * 256 + tid] +
                 part[32768 + b * 256 + tid] + part[49152 + b * 256 + tid];
            float v2 = wave_sum(yb * yb);
            if ((tid & 63) == 0) wred[tid >> 6] = v2;
        }
        __syncthreads();
        float inv2 = rsqrtf((wred[0] + wred[1] + wred[2] + wred[3]) *
                            (1.0f / 256.0f) + EPSV);
        if (tid < 256) g[tid] = yb * inv2 * onorm[tid];
        __syncthreads();

        const float4* xx = reinterpret_cast<const float4*>(x) +
                           (size_t)b * 16384 + q * 4096;
        float4* oo = reinterpret_cast<float4*>(out) +
                     (size_t)b * 16384 + q * 4096;
#pragma unroll
        for (int i = tid; i < 4096; i += NTHR) {
            int row = (q * 4096 + i) >> 6;
            float4 xv = xx[i];
            float gg = g[row];
            oo[i] = make_float4(xv.x + gg, xv.y + gg, xv.z + gg, xv.w + gg);
        }
    }
}

extern "C" void kernel_launch(void* const* d_in, const int* in_sizes, int n_in,
                              void* d_out, int out_size, void* d_ws, size_t ws_size,
                              hipStream_t stream) {
    const float* x     = (const float*)d_in[0];
    const float* temb  = (const float*)d_in[1];
    const float* mlp_w = (const float*)d_in[2];
    const float* mlp_b = (const float*)d_in[3];
    const float* qkv_w = (const float*)d_in[4];
    const float* out_w = (const float*)d_in[5];
    const float* out_b = (const float*)d_in[6];
    const float* onorm = (const float*)d_in[7];
    float* out = (float*)d_out;
    float* ws  = (float*)d_ws;

    // zero barrier flags+gen (SDMA fill node: measured ~free vs kernel nodes)
    hipMemsetAsync(ws, 0, 32768, stream);
    k_fused<<<NBLK, NTHR, 0, stream>>>(x, temb, mlp_w, mlp_b, qkv_w,
                                       out_w, out_b, onorm, out, ws);
}